// Round 1
// baseline (1120.353 us; speedup 1.0000x reference)
//
#include <hip/hip_runtime.h>
#include <hip/hip_bf16.h>

#define TOK 8192      // B*N
#define CDIM 384
#define HEADS 6
#define DH 64
#define HID 1536
#define SEQ 2048

__device__ __forceinline__ float gelu_exact(float v) {
    return 0.5f * v * (1.0f + erff(v * 0.70710678118654752f));
}

// -------------------- LayerNorm: one block (128 thr) per row of 384 --------------------
__global__ __launch_bounds__(128) void ln_kernel(const float* __restrict__ x,
                                                 const float* __restrict__ g,
                                                 const float* __restrict__ bta,
                                                 float* __restrict__ y) {
    const int row = blockIdx.x;
    const float* xr = x + (size_t)row * CDIM;
    const int t = threadIdx.x;
    float v0 = xr[t], v1 = xr[t + 128], v2 = xr[t + 256];
    float s = v0 + v1 + v2;
    float ss = v0 * v0 + v1 * v1 + v2 * v2;
#pragma unroll
    for (int off = 1; off < 64; off <<= 1) {
        s += __shfl_xor(s, off);
        ss += __shfl_xor(ss, off);
    }
    __shared__ float sh[4];
    const int wv = t >> 6;
    if ((t & 63) == 0) { sh[wv] = s; sh[2 + wv] = ss; }
    __syncthreads();
    s = sh[0] + sh[1];
    ss = sh[2] + sh[3];
    const float mu = s * (1.0f / CDIM);
    const float var = ss * (1.0f / CDIM) - mu * mu;
    const float rs = rsqrtf(var + 1e-6f);
    float* yr = y + (size_t)row * CDIM;
    yr[t]       = (v0 - mu) * rs * g[t]       + bta[t];
    yr[t + 128] = (v1 - mu) * rs * g[t + 128] + bta[t + 128];
    yr[t + 256] = (v2 - mu) * rs * g[t + 256] + bta[t + 256];
}

// -------------------- fp32 tiled GEMM: C = act(A[M,K] @ W[K,N] + bias) (+ resid) ------
// BM=64, BN=64, BK=16, 256 threads, 4x4 microtile per thread.
__global__ __launch_bounds__(256) void gemm_kernel(const float* __restrict__ A,
                                                   const float* __restrict__ W,
                                                   const float* __restrict__ bias,
                                                   const float* __restrict__ resid,
                                                   float* __restrict__ C,
                                                   int M, int N, int K, int act) {
    __shared__ __align__(16) float As[16][64];  // As[k][m]
    __shared__ __align__(16) float Bs[16][64];  // Bs[k][n]
    const int tid = threadIdx.x;
    const int tx = tid & 15;      // col group
    const int ty = tid >> 4;      // row group
    const int row0 = blockIdx.y * 64;
    const int col0 = blockIdx.x * 64;

    const int lrow = tid >> 2;          // 0..63 (A row within tile)
    const int lk4  = (tid & 3) * 4;     // k chunk
    const int wk   = tid >> 4;          // 0..15 (W k-row within tile)
    const int wc4  = (tid & 15) * 4;    // col chunk

    float acc[4][4] = {};

    for (int k0 = 0; k0 < K; k0 += 16) {
        const float4 av = *(const float4*)(A + (size_t)(row0 + lrow) * K + k0 + lk4);
        const float4 wv = *(const float4*)(W + (size_t)(k0 + wk) * N + col0 + wc4);
        __syncthreads();
        As[lk4 + 0][lrow] = av.x;
        As[lk4 + 1][lrow] = av.y;
        As[lk4 + 2][lrow] = av.z;
        As[lk4 + 3][lrow] = av.w;
        *(float4*)&Bs[wk][wc4] = wv;
        __syncthreads();
#pragma unroll
        for (int k = 0; k < 16; ++k) {
            const float4 a4 = *(const float4*)&As[k][ty * 4];
            const float4 b4 = *(const float4*)&Bs[k][tx * 4];
            const float ar[4] = {a4.x, a4.y, a4.z, a4.w};
            const float br[4] = {b4.x, b4.y, b4.z, b4.w};
#pragma unroll
            for (int i = 0; i < 4; ++i)
#pragma unroll
                for (int j = 0; j < 4; ++j)
                    acc[i][j] += ar[i] * br[j];
        }
    }

    const int c0 = col0 + tx * 4;
    const float4 bv = *(const float4*)(bias + c0);
#pragma unroll
    for (int i = 0; i < 4; ++i) {
        const int r = row0 + ty * 4 + i;
        float4 o;
        o.x = acc[i][0] + bv.x;
        o.y = acc[i][1] + bv.y;
        o.z = acc[i][2] + bv.z;
        o.w = acc[i][3] + bv.w;
        if (act == 1) {
            o.x = gelu_exact(o.x);
            o.y = gelu_exact(o.y);
            o.z = gelu_exact(o.z);
            o.w = gelu_exact(o.w);
        }
        if (resid) {
            const float4 rv = *(const float4*)(resid + (size_t)r * N + c0);
            o.x += rv.x; o.y += rv.y; o.z += rv.z; o.w += rv.w;
        }
        *(float4*)(C + (size_t)r * N + c0) = o;
    }
}

// -------------------- flash attention, fp32, 64q x 64k tiles --------------------
// grid: (SEQ/64, HEADS, B), block 256. qkv layout [B,N,3,H,DH].
__global__ __launch_bounds__(256) void attn_kernel(const float* __restrict__ qkv,
                                                   float* __restrict__ outp) {
    const int qt = blockIdx.x;
    const int h  = blockIdx.y;
    const int b  = blockIdx.z;

    __shared__ __align__(16) float Qt[64][64];  // Qt[d][q], pre-scaled
    __shared__ __align__(16) float Kt[64][64];  // Kt[d][k]
    __shared__ __align__(16) float Vs[64][64];  // Vs[k][d]
    __shared__ __align__(16) float Pt[64][64];  // Pt[k][q]

    const int tid = threadIdx.x;
    const int tx = tid & 15;   // d-col group (and k-col group for S)
    const int ty = tid >> 4;   // q-row group

    const int lr = tid >> 2;          // 0..63: row within tile
    const int lp = (tid & 3) * 16;    // 16-float chunk of the 64-dim

    const size_t bn = (size_t)b * SEQ;
    const float scale = 0.125f;  // 1/sqrt(64)

    {
        const float* qrow = qkv + ((bn + qt * 64 + lr) * 3 + 0) * CDIM + h * DH;
#pragma unroll
        for (int c = 0; c < 4; ++c) {
            const float4 v = *(const float4*)(qrow + lp + c * 4);
            Qt[lp + c * 4 + 0][lr] = v.x * scale;
            Qt[lp + c * 4 + 1][lr] = v.y * scale;
            Qt[lp + c * 4 + 2][lr] = v.z * scale;
            Qt[lp + c * 4 + 3][lr] = v.w * scale;
        }
    }

    float m[4], l[4], O[4][4] = {};
#pragma unroll
    for (int i = 0; i < 4; ++i) { m[i] = -1e30f; l[i] = 0.0f; }

    for (int kt = 0; kt < SEQ / 64; ++kt) {
        __syncthreads();  // prev iteration's reads of Kt/Vs/Pt done
        const float* krow = qkv + ((bn + kt * 64 + lr) * 3 + 1) * CDIM + h * DH;
        const float* vrow = qkv + ((bn + kt * 64 + lr) * 3 + 2) * CDIM + h * DH;
#pragma unroll
        for (int c = 0; c < 4; ++c) {
            const float4 kv = *(const float4*)(krow + lp + c * 4);
            Kt[lp + c * 4 + 0][lr] = kv.x;
            Kt[lp + c * 4 + 1][lr] = kv.y;
            Kt[lp + c * 4 + 2][lr] = kv.z;
            Kt[lp + c * 4 + 3][lr] = kv.w;
            *(float4*)&Vs[lr][lp + c * 4] = *(const float4*)(vrow + lp + c * 4);
        }
        __syncthreads();

        // S tile: s[i][j] = sum_d Qt[d][ty*4+i] * Kt[d][tx*4+j]
        float s[4][4] = {};
#pragma unroll
        for (int d = 0; d < 64; ++d) {
            const float4 q4 = *(const float4*)&Qt[d][ty * 4];
            const float4 k4 = *(const float4*)&Kt[d][tx * 4];
            const float qa[4] = {q4.x, q4.y, q4.z, q4.w};
            const float ka[4] = {k4.x, k4.y, k4.z, k4.w};
#pragma unroll
            for (int i = 0; i < 4; ++i)
#pragma unroll
                for (int j = 0; j < 4; ++j)
                    s[i][j] += qa[i] * ka[j];
        }

        // row max across the 16 lanes of the tx-group (lanes differ only in bits 0..3)
        float rmax[4];
#pragma unroll
        for (int i = 0; i < 4; ++i)
            rmax[i] = fmaxf(fmaxf(s[i][0], s[i][1]), fmaxf(s[i][2], s[i][3]));
#pragma unroll
        for (int off = 1; off < 16; off <<= 1)
#pragma unroll
            for (int i = 0; i < 4; ++i)
                rmax[i] = fmaxf(rmax[i], __shfl_xor(rmax[i], off));

        float p[4][4];
        float rsum[4];
#pragma unroll
        for (int i = 0; i < 4; ++i) {
            const float mnew = fmaxf(m[i], rmax[i]);
            const float alpha = __expf(m[i] - mnew);
            m[i] = mnew;
            l[i] *= alpha;
#pragma unroll
            for (int j = 0; j < 4; ++j) O[i][j] *= alpha;
            float rs = 0.0f;
#pragma unroll
            for (int j = 0; j < 4; ++j) {
                p[i][j] = __expf(s[i][j] - mnew);
                rs += p[i][j];
            }
            rsum[i] = rs;
        }
#pragma unroll
        for (int off = 1; off < 16; off <<= 1)
#pragma unroll
            for (int i = 0; i < 4; ++i)
                rsum[i] += __shfl_xor(rsum[i], off);
#pragma unroll
        for (int i = 0; i < 4; ++i) l[i] += rsum[i];

        // write P transposed: Pt[k][q]
#pragma unroll
        for (int j = 0; j < 4; ++j) {
            float4 pv;
            pv.x = p[0][j]; pv.y = p[1][j]; pv.z = p[2][j]; pv.w = p[3][j];
            *(float4*)&Pt[tx * 4 + j][ty * 4] = pv;
        }
        __syncthreads();

        // O[i][j] += sum_k Pt[k][ty*4+i] * Vs[k][tx*4+j]
#pragma unroll
        for (int k = 0; k < 64; ++k) {
            const float4 p4 = *(const float4*)&Pt[k][ty * 4];
            const float4 v4 = *(const float4*)&Vs[k][tx * 4];
            const float pa[4] = {p4.x, p4.y, p4.z, p4.w};
            const float va[4] = {v4.x, v4.y, v4.z, v4.w};
#pragma unroll
            for (int i = 0; i < 4; ++i)
#pragma unroll
                for (int j = 0; j < 4; ++j)
                    O[i][j] += pa[i] * va[j];
        }
    }

    // normalize and store: out[b, qt*64 + ty*4+i, h*64 + tx*4 .. +3]
#pragma unroll
    for (int i = 0; i < 4; ++i) {
        const float inv = 1.0f / l[i];
        float4 o;
        o.x = O[i][0] * inv; o.y = O[i][1] * inv; o.z = O[i][2] * inv; o.w = O[i][3] * inv;
        *(float4*)(outp + (bn + qt * 64 + ty * 4 + i) * CDIM + h * DH + tx * 4) = o;
    }
}

extern "C" void kernel_launch(void* const* d_in, const int* in_sizes, int n_in,
                              void* d_out, int out_size, void* d_ws, size_t ws_size,
                              hipStream_t stream) {
    const float* x      = (const float*)d_in[0];
    const float* w_qkv  = (const float*)d_in[1];
    const float* b_qkv  = (const float*)d_in[2];
    const float* w_proj = (const float*)d_in[3];
    const float* b_proj = (const float*)d_in[4];
    const float* w_fc1  = (const float*)d_in[5];
    const float* b_fc1  = (const float*)d_in[6];
    const float* w_fc2  = (const float*)d_in[7];
    const float* b_fc2  = (const float*)d_in[8];
    const float* g1     = (const float*)d_in[9];
    const float* beta1  = (const float*)d_in[10];
    const float* g2     = (const float*)d_in[11];
    const float* beta2  = (const float*)d_in[12];
    float* out = (float*)d_out;

    // ws layout: y (12.58 MB) | big (50.33 MB). big holds qkv (37.75 MB) with
    // attn-out in its tail (12.58 MB); later fully overwritten by MLP hidden h.
    char* ws = (char*)d_ws;
    float* y    = (float*)ws;
    float* big  = (float*)(ws + (size_t)TOK * CDIM * 4);
    float* qkvb = big;
    float* attn = (float*)((char*)big + (size_t)TOK * 3 * CDIM * 4);
    float* hbuf = big;

    // 1) y = LN(x, g1, beta1)
    ln_kernel<<<TOK, 128, 0, stream>>>(x, g1, beta1, y);
    // 2) qkv = y @ w_qkv + b_qkv
    gemm_kernel<<<dim3(3 * CDIM / 64, TOK / 64), 256, 0, stream>>>(
        y, w_qkv, b_qkv, nullptr, qkvb, TOK, 3 * CDIM, CDIM, 0);
    // 3) attn = flash_attention(qkv)
    attn_kernel<<<dim3(SEQ / 64, HEADS, 4), 256, 0, stream>>>(qkvb, attn);
    // 4) out(x1) = x + attn @ w_proj + b_proj
    gemm_kernel<<<dim3(CDIM / 64, TOK / 64), 256, 0, stream>>>(
        attn, w_proj, b_proj, x, out, TOK, CDIM, CDIM, 0);
    // 5) y = LN(x1, g2, beta2)
    ln_kernel<<<TOK, 128, 0, stream>>>(out, g2, beta2, y);
    // 6) h = gelu(y @ w_fc1 + b_fc1)
    gemm_kernel<<<dim3(HID / 64, TOK / 64), 256, 0, stream>>>(
        y, w_fc1, b_fc1, nullptr, hbuf, TOK, HID, CDIM, 1);
    // 7) out = x1 + h @ w_fc2 + b_fc2   (in-place residual: 1 thread per element)
    gemm_kernel<<<dim3(CDIM / 64, TOK / 64), 256, 0, stream>>>(
        hbuf, w_fc2, b_fc2, out, out, TOK, CDIM, HID, 0);
}

// Round 2
// 631.623 us; speedup vs baseline: 1.7738x; 1.7738x over previous
//
#include <hip/hip_runtime.h>
#include <hip/hip_bf16.h>

#define TOK 8192      // B*N
#define CDIM 384
#define HEADS 6
#define DH 64
#define HID 1536
#define SEQ 2048

typedef short bf16x8 __attribute__((ext_vector_type(8)));
typedef float f32x4 __attribute__((ext_vector_type(4)));
typedef void __attribute__((address_space(1))) GV;
typedef void __attribute__((address_space(3))) SV;

__device__ __forceinline__ short f2bf(float f) {
    __hip_bfloat16 h = __float2bfloat16(f);
    return *reinterpret_cast<short*>(&h);
}

__device__ __forceinline__ void gl_lds16(const short* g, short* lds) {
    // loads 16B per lane: lane i's global data -> lds_base + i*16
    __builtin_amdgcn_global_load_lds((GV*)g, (SV*)lds, 16, 0, 0);
}

__device__ __forceinline__ float gelu_exact(float v) {
    return 0.5f * v * (1.0f + erff(v * 0.70710678118654752f));
}

// -------------------- LayerNorm: one block (128 thr) per row of 384 --------------------
__global__ __launch_bounds__(128) void ln_kernel(const float* __restrict__ x,
                                                 const float* __restrict__ g,
                                                 const float* __restrict__ bta,
                                                 float* __restrict__ y) {
    const int row = blockIdx.x;
    const float* xr = x + (size_t)row * CDIM;
    const int t = threadIdx.x;
    float v0 = xr[t], v1 = xr[t + 128], v2 = xr[t + 256];
    float s = v0 + v1 + v2;
    float ss = v0 * v0 + v1 * v1 + v2 * v2;
#pragma unroll
    for (int off = 1; off < 64; off <<= 1) {
        s += __shfl_xor(s, off);
        ss += __shfl_xor(ss, off);
    }
    __shared__ float sh[4];
    const int wv = t >> 6;
    if ((t & 63) == 0) { sh[wv] = s; sh[2 + wv] = ss; }
    __syncthreads();
    s = sh[0] + sh[1];
    ss = sh[2] + sh[3];
    const float mu = s * (1.0f / CDIM);
    const float var = ss * (1.0f / CDIM) - mu * mu;
    const float rs = rsqrtf(var + 1e-6f);
    float* yr = y + (size_t)row * CDIM;
    yr[t]       = (v0 - mu) * rs * g[t]       + bta[t];
    yr[t + 128] = (v1 - mu) * rs * g[t + 128] + bta[t + 128];
    yr[t + 256] = (v2 - mu) * rs * g[t + 256] + bta[t + 256];
}

// -------------------- fp32 tiled GEMM --------------------
// act: 0 = bias (+resid), 1 = bias+gelu, 2 = qkv epilogue -> bf16 q/k/vt buffers
__global__ __launch_bounds__(256) void gemm_kernel(const float* __restrict__ A,
                                                   const float* __restrict__ W,
                                                   const float* __restrict__ bias,
                                                   const float* __restrict__ resid,
                                                   float* __restrict__ C,
                                                   short* __restrict__ qb,
                                                   short* __restrict__ kb,
                                                   short* __restrict__ vtb,
                                                   int M, int N, int K, int act) {
    __shared__ __align__(16) float As[16][64];  // As[k][m]
    __shared__ __align__(16) float Bs[16][64];  // Bs[k][n]
    const int tid = threadIdx.x;
    const int tx = tid & 15;      // col group
    const int ty = tid >> 4;      // row group
    const int row0 = blockIdx.y * 64;
    const int col0 = blockIdx.x * 64;

    const int lrow = tid >> 2;          // 0..63 (A row within tile)
    const int lk4  = (tid & 3) * 4;     // k chunk
    const int wk   = tid >> 4;          // 0..15 (W k-row within tile)
    const int wc4  = (tid & 15) * 4;    // col chunk

    float acc[4][4] = {};

    for (int k0 = 0; k0 < K; k0 += 16) {
        const float4 av = *(const float4*)(A + (size_t)(row0 + lrow) * K + k0 + lk4);
        const float4 wv = *(const float4*)(W + (size_t)(k0 + wk) * N + col0 + wc4);
        __syncthreads();
        As[lk4 + 0][lrow] = av.x;
        As[lk4 + 1][lrow] = av.y;
        As[lk4 + 2][lrow] = av.z;
        As[lk4 + 3][lrow] = av.w;
        *(float4*)&Bs[wk][wc4] = wv;
        __syncthreads();
#pragma unroll
        for (int k = 0; k < 16; ++k) {
            const float4 a4 = *(const float4*)&As[k][ty * 4];
            const float4 b4 = *(const float4*)&Bs[k][tx * 4];
            const float ar[4] = {a4.x, a4.y, a4.z, a4.w};
            const float br[4] = {b4.x, b4.y, b4.z, b4.w};
#pragma unroll
            for (int i = 0; i < 4; ++i)
#pragma unroll
                for (int j = 0; j < 4; ++j)
                    acc[i][j] += ar[i] * br[j];
        }
    }

    const int c0 = col0 + tx * 4;
    const float4 bv = *(const float4*)(bias + c0);

    if (act == 2) {
        // qkv epilogue: col0 is a multiple of 64 -> whole block is one (part, head)
        const int part = col0 / CDIM;             // 0=q, 1=k, 2=v
        const int h = (col0 % CDIM) >> 6;
        const int d0 = tx * 4;                    // d within head (col0%64 == 0)
#pragma unroll
        for (int i = 0; i < 4; ++i) {
            const int r = row0 + ty * 4 + i;      // global token
            const int bi = r >> 11;               // batch
            const int n = r & 2047;               // position
            float o[4] = {acc[i][0] + bv.x, acc[i][1] + bv.y,
                          acc[i][2] + bv.z, acc[i][3] + bv.w};
            if (part < 2) {
                short* dst = (part == 0 ? qb : kb) +
                             ((size_t)(bi * HEADS + h) * SEQ + n) * DH + d0;
                short4 pk;
                pk.x = f2bf(o[0]); pk.y = f2bf(o[1]);
                pk.z = f2bf(o[2]); pk.w = f2bf(o[3]);
                *(short4*)dst = pk;
            } else {
#pragma unroll
                for (int j = 0; j < 4; ++j)
                    vtb[((size_t)(bi * HEADS + h) * DH + d0 + j) * SEQ + n] = f2bf(o[j]);
            }
        }
        return;
    }

#pragma unroll
    for (int i = 0; i < 4; ++i) {
        const int r = row0 + ty * 4 + i;
        float4 o;
        o.x = acc[i][0] + bv.x;
        o.y = acc[i][1] + bv.y;
        o.z = acc[i][2] + bv.z;
        o.w = acc[i][3] + bv.w;
        if (act == 1) {
            o.x = gelu_exact(o.x);
            o.y = gelu_exact(o.y);
            o.z = gelu_exact(o.z);
            o.w = gelu_exact(o.w);
        }
        if (resid) {
            const float4 rv = *(const float4*)(resid + (size_t)r * N + c0);
            o.x += rv.x; o.y += rv.y; o.z += rv.z; o.w += rv.w;
        }
        *(float4*)(C + (size_t)r * N + c0) = o;
    }
}

// -------------------- bf16 MFMA flash attention --------------------
// grid (SEQ/64, HEADS, B), block 256 (4 waves). Wave w owns q-rows w*16..w*16+15.
// Q,K: bf16 [B,H,N,DH] row-major; Vt: bf16 [B,H,DH,N].
__global__ __launch_bounds__(256) void attn_mfma(const short* __restrict__ qb,
                                                 const short* __restrict__ kb,
                                                 const short* __restrict__ vtb,
                                                 float* __restrict__ outp) {
    __shared__ __align__(16) short Ql[64 * 64];       // [q][d]
    __shared__ __align__(16) short Kl[64 * 64];       // [kcol][d]
    __shared__ __align__(16) short Vtl[64 * 64];      // [d][kcol]
    __shared__ __align__(16) short Pl[4 * 16 * 72];   // per-wave [q16][k64+pad8]

    const int qt = blockIdx.x;
    const int h  = blockIdx.y;
    const int b  = blockIdx.z;
    const int bh = b * HEADS + h;

    const int tid  = threadIdx.x;
    const int w    = tid >> 6;
    const int lane = tid & 63;
    const int quad = lane >> 4;
    const int n15  = lane & 15;

    const size_t headoff = (size_t)bh * SEQ * DH;   // shorts

    // stage Q tile (rows qt*64..+63, contiguous 8KB)
    {
        const short* qg = qb + headoff + (size_t)qt * 64 * DH;
#pragma unroll
        for (int i = 0; i < 2; ++i) {
            const int c = (w * 2 + i) * 512;   // shorts
            gl_lds16(qg + c + lane * 8, Ql + c);
        }
    }

    f32x4 O[4];
    float m[4], l[4];
#pragma unroll
    for (int nt = 0; nt < 4; ++nt) { O[nt][0] = 0; O[nt][1] = 0; O[nt][2] = 0; O[nt][3] = 0; }
#pragma unroll
    for (int r = 0; r < 4; ++r) { m[r] = -1e30f; l[r] = 0.0f; }

    bf16x8 qf[2];
    short* myPl = Pl + w * (16 * 72);

    for (int kt = 0; kt < SEQ / 64; ++kt) {
        __syncthreads();   // prior iteration's LDS reads done
        {
            const short* kg = kb + headoff + (size_t)kt * 64 * DH;
#pragma unroll
            for (int i = 0; i < 2; ++i) {
                const int c = (w * 2 + i) * 512;
                gl_lds16(kg + c + lane * 8, Kl + c);
            }
#pragma unroll
            for (int i = 0; i < 2; ++i) {
                const int c = (w * 2 + i) * 512;
                const int o16 = (w * 2 + i) * 64 + lane;   // 16B chunk index
                const int d = o16 >> 3;
                const int inr = (o16 & 7) * 8;             // shorts within Vt row
                const short* vg = vtb + (size_t)bh * DH * SEQ + (size_t)d * SEQ + kt * 64 + inr;
                gl_lds16(vg, Vtl + c);
            }
        }
        __syncthreads();   // staging visible (vmcnt drained by barrier)

        if (kt == 0) {
            qf[0] = *(const bf16x8*)&Ql[(w * 16 + n15) * 64 + quad * 8];
            qf[1] = *(const bf16x8*)&Ql[(w * 16 + n15) * 64 + 32 + quad * 8];
        }

        // S = Q K^T  (wave: 16 q-rows x 64 k-cols; 4 n-tiles x 2 k-chunks)
        f32x4 S[4];
#pragma unroll
        for (int nt = 0; nt < 4; ++nt) {
            S[nt][0] = 0; S[nt][1] = 0; S[nt][2] = 0; S[nt][3] = 0;
#pragma unroll
            for (int kc = 0; kc < 2; ++kc) {
                const bf16x8 kf = *(const bf16x8*)&Kl[(nt * 16 + n15) * 64 + kc * 32 + quad * 8];
                S[nt] = __builtin_amdgcn_mfma_f32_16x16x32_bf16(qf[kc], kf, S[nt], 0, 0, 0);
            }
        }

        // online softmax. C-layout: reg r -> q-row quad*4+r, lane&15 -> k-col within n-tile.
        float sc[4][4];    // [nt][r]
#pragma unroll
        for (int nt = 0; nt < 4; ++nt)
#pragma unroll
            for (int r = 0; r < 4; ++r)
                sc[nt][r] = S[nt][r] * 0.125f;

        float rm[4];
#pragma unroll
        for (int r = 0; r < 4; ++r)
            rm[r] = fmaxf(fmaxf(sc[0][r], sc[1][r]), fmaxf(sc[2][r], sc[3][r]));
#pragma unroll
        for (int off = 1; off < 16; off <<= 1)
#pragma unroll
            for (int r = 0; r < 4; ++r)
                rm[r] = fmaxf(rm[r], __shfl_xor(rm[r], off));

        float alpha[4], rs[4];
#pragma unroll
        for (int r = 0; r < 4; ++r) {
            const float mn = fmaxf(m[r], rm[r]);
            alpha[r] = __expf(m[r] - mn);
            m[r] = mn;
            float acc = 0.0f;
#pragma unroll
            for (int nt = 0; nt < 4; ++nt) {
                const float p = __expf(sc[nt][r] - mn);
                sc[nt][r] = p;
                acc += p;
            }
            rs[r] = acc;
        }
#pragma unroll
        for (int off = 1; off < 16; off <<= 1)
#pragma unroll
            for (int r = 0; r < 4; ++r)
                rs[r] += __shfl_xor(rs[r], off);
#pragma unroll
        for (int r = 0; r < 4; ++r)
            l[r] = l[r] * alpha[r] + rs[r];

        // rescale O and stage P (C-layout -> A-layout via per-wave LDS)
#pragma unroll
        for (int nt = 0; nt < 4; ++nt)
#pragma unroll
            for (int r = 0; r < 4; ++r) {
                O[nt][r] *= alpha[r];
                myPl[(quad * 4 + r) * 72 + nt * 16 + n15] = f2bf(sc[nt][r]);
            }

        // O += P V  (A = P from myPl, B = V from Vtl)
        bf16x8 pf[2];
        pf[0] = *(const bf16x8*)&myPl[n15 * 72 + quad * 8];
        pf[1] = *(const bf16x8*)&myPl[n15 * 72 + 32 + quad * 8];
#pragma unroll
        for (int nt = 0; nt < 4; ++nt) {
#pragma unroll
            for (int kc = 0; kc < 2; ++kc) {
                const bf16x8 vf = *(const bf16x8*)&Vtl[(nt * 16 + n15) * 64 + kc * 32 + quad * 8];
                O[nt] = __builtin_amdgcn_mfma_f32_16x16x32_bf16(pf[kc], vf, O[nt], 0, 0, 0);
            }
        }
    }

    float inv[4];
#pragma unroll
    for (int r = 0; r < 4; ++r) inv[r] = 1.0f / l[r];
#pragma unroll
    for (int nt = 0; nt < 4; ++nt)
#pragma unroll
        for (int r = 0; r < 4; ++r) {
            const int row = qt * 64 + w * 16 + quad * 4 + r;
            outp[(size_t)(b * SEQ + row) * CDIM + h * DH + nt * 16 + n15] = O[nt][r] * inv[r];
        }
}

extern "C" void kernel_launch(void* const* d_in, const int* in_sizes, int n_in,
                              void* d_out, int out_size, void* d_ws, size_t ws_size,
                              hipStream_t stream) {
    const float* x      = (const float*)d_in[0];
    const float* w_qkv  = (const float*)d_in[1];
    const float* b_qkv  = (const float*)d_in[2];
    const float* w_proj = (const float*)d_in[3];
    const float* b_proj = (const float*)d_in[4];
    const float* w_fc1  = (const float*)d_in[5];
    const float* b_fc1  = (const float*)d_in[6];
    const float* w_fc2  = (const float*)d_in[7];
    const float* b_fc2  = (const float*)d_in[8];
    const float* g1     = (const float*)d_in[9];
    const float* beta1  = (const float*)d_in[10];
    const float* g2     = (const float*)d_in[11];
    const float* beta2  = (const float*)d_in[12];
    float* out = (float*)d_out;

    // ws layout (62.9 MB total):
    //   y   fp32 [TOK][384]            @ 0         (12.58 MB)  — LN out, then attn out, then LN2 out
    //   big                            @ 12.58 MB  (50.33 MB)  — first bf16 q/k/vt (18.9 MB), later fc1 h
    char* ws = (char*)d_ws;
    float* y   = (float*)ws;
    char*  big = ws + (size_t)TOK * CDIM * 4;
    short* qb  = (short*)big;
    short* kb  = qb + (size_t)TOK * CDIM;
    short* vtb = kb + (size_t)TOK * CDIM;
    float* hbuf = (float*)big;
    float* attn = y;   // reuse: LN1 output consumed by qkv gemm before attn writes

    // 1) y = LN(x, g1, beta1)
    ln_kernel<<<TOK, 128, 0, stream>>>(x, g1, beta1, y);
    // 2) q/k/vt (bf16) = y @ w_qkv + b_qkv
    gemm_kernel<<<dim3(3 * CDIM / 64, TOK / 64), 256, 0, stream>>>(
        y, w_qkv, b_qkv, nullptr, nullptr, qb, kb, vtb, TOK, 3 * CDIM, CDIM, 2);
    // 3) attn = flash_attention(q, k, vt)  [bf16 MFMA]
    attn_mfma<<<dim3(SEQ / 64, HEADS, 4), 256, 0, stream>>>(qb, kb, vtb, attn);
    // 4) out(x1) = x + attn @ w_proj + b_proj
    gemm_kernel<<<dim3(CDIM / 64, TOK / 64), 256, 0, stream>>>(
        attn, w_proj, b_proj, x, out, nullptr, nullptr, nullptr, TOK, CDIM, CDIM, 0);
    // 5) y = LN(x1, g2, beta2)
    ln_kernel<<<TOK, 128, 0, stream>>>(out, g2, beta2, y);
    // 6) h = gelu(y @ w_fc1 + b_fc1)
    gemm_kernel<<<dim3(HID / 64, TOK / 64), 256, 0, stream>>>(
        y, w_fc1, b_fc1, nullptr, hbuf, nullptr, nullptr, nullptr, TOK, HID, CDIM, 1);
    // 7) out = x1 + h @ w_fc2 + b_fc2   (in-place residual: 1 thread per element)
    gemm_kernel<<<dim3(CDIM / 64, TOK / 64), 256, 0, stream>>>(
        hbuf, w_fc2, b_fc2, out, out, nullptr, nullptr, nullptr, TOK, CDIM, HID, 0);
}

// Round 3
// 344.521 us; speedup vs baseline: 3.2519x; 1.8333x over previous
//
#include <hip/hip_runtime.h>
#include <hip/hip_bf16.h>

#define TOK 8192      // B*N
#define CDIM 384
#define HEADS 6
#define DH 64
#define HID 1536
#define SEQ 2048

typedef short bf16x8 __attribute__((ext_vector_type(8)));
typedef float f32x4 __attribute__((ext_vector_type(4)));
typedef void __attribute__((address_space(1))) GV;
typedef void __attribute__((address_space(3))) SV;

__device__ __forceinline__ short f2bf(float f) {
    __hip_bfloat16 h = __float2bfloat16(f);
    return *reinterpret_cast<short*>(&h);
}

__device__ __forceinline__ void gl_lds16(const short* g, short* lds) {
    // wave-collective: lane i's 16B -> lds_base + i*16 (lds must be wave-uniform)
    __builtin_amdgcn_global_load_lds((GV*)g, (SV*)lds, 16, 0, 0);
}

__device__ __forceinline__ float gelu_exact(float v) {
    return 0.5f * v * (1.0f + erff(v * 0.70710678118654752f));
}

// -------------------- LayerNorm: fp32 in, bf16 out --------------------
__global__ __launch_bounds__(128) void ln_kernel(const float* __restrict__ x,
                                                 const float* __restrict__ g,
                                                 const float* __restrict__ bta,
                                                 short* __restrict__ y) {
    const int row = blockIdx.x;
    const float* xr = x + (size_t)row * CDIM;
    const int t = threadIdx.x;
    float v0 = xr[t], v1 = xr[t + 128], v2 = xr[t + 256];
    float s = v0 + v1 + v2;
    float ss = v0 * v0 + v1 * v1 + v2 * v2;
#pragma unroll
    for (int off = 1; off < 64; off <<= 1) {
        s += __shfl_xor(s, off);
        ss += __shfl_xor(ss, off);
    }
    __shared__ float sh[4];
    const int wv = t >> 6;
    if ((t & 63) == 0) { sh[wv] = s; sh[2 + wv] = ss; }
    __syncthreads();
    s = sh[0] + sh[1];
    ss = sh[2] + sh[3];
    const float mu = s * (1.0f / CDIM);
    const float var = ss * (1.0f / CDIM) - mu * mu;
    const float rs = rsqrtf(var + 1e-6f);
    short* yr = y + (size_t)row * CDIM;
    yr[t]       = f2bf((v0 - mu) * rs * g[t]       + bta[t]);
    yr[t + 128] = f2bf((v1 - mu) * rs * g[t + 128] + bta[t + 128]);
    yr[t + 256] = f2bf((v2 - mu) * rs * g[t + 256] + bta[t + 256]);
}

// -------------------- weight transpose+convert: wT[n][k] = bf16(w[k][n]) ----------
__global__ __launch_bounds__(256) void transpose_bf16(const float* __restrict__ w,
                                                      short* __restrict__ wT,
                                                      int K, int N) {
    __shared__ float t[32][33];
    const int bx = blockIdx.x * 32, by = blockIdx.y * 32;
    const int tx = threadIdx.x & 31, ty = threadIdx.x >> 5;
#pragma unroll
    for (int i = 0; i < 4; ++i)
        t[ty + i * 8][tx] = w[(size_t)(by + ty + i * 8) * N + bx + tx];
    __syncthreads();
#pragma unroll
    for (int i = 0; i < 4; ++i)
        wT[(size_t)(bx + ty + i * 8) * K + by + tx] = f2bf(t[tx][ty + i * 8]);
}

// -------------------- bf16 MFMA GEMM: C = A[M,K] @ WT[N,K]^T + bias ----------------
// 128x128 tile, BK=32, 256 threads (4 waves, 2x2), 4x4 mfma 16x16x32 per wave.
// MODE 0: fp32 out (+optional resid).  MODE 1: gelu -> bf16 out.  MODE 2: qkv scatter.
template <int MODE>
__global__ __launch_bounds__(256) void mfma_gemm(const short* __restrict__ A,
                                                 const short* __restrict__ WT,
                                                 const float* __restrict__ bias,
                                                 const float* __restrict__ resid,
                                                 float* __restrict__ outF,
                                                 short* __restrict__ outB,
                                                 short* __restrict__ qb,
                                                 short* __restrict__ kb,
                                                 short* __restrict__ vtb,
                                                 int M, int N, int K) {
    __shared__ __align__(16) short As[128 * 32];
    __shared__ __align__(16) short Bs[128 * 32];

    const int tid  = threadIdx.x;
    const int w    = tid >> 6;
    const int lane = tid & 63;
    const int quad = lane >> 4;
    const int n15  = lane & 15;
    const int wr   = w >> 1;
    const int wc   = w & 1;
    const int m0   = blockIdx.y * 128;
    const int n0   = blockIdx.x * 128;

    f32x4 acc[4][4];
#pragma unroll
    for (int i = 0; i < 4; ++i)
#pragma unroll
        for (int j = 0; j < 4; ++j) {
            acc[i][j][0] = 0; acc[i][j][1] = 0; acc[i][j][2] = 0; acc[i][j][3] = 0;
        }

    // staging chunk ids (16B each): A/B tile = 512 chunks, 2 issues of 256
    const int ca0 = tid, ca1 = tid + 256;

    for (int k0 = 0; k0 < K; k0 += 32) {
        __syncthreads();
        gl_lds16(A  + (size_t)(m0 + (ca0 >> 2)) * K + k0 + (ca0 & 3) * 8, As + w * 512);
        gl_lds16(A  + (size_t)(m0 + (ca1 >> 2)) * K + k0 + (ca1 & 3) * 8, As + 2048 + w * 512);
        gl_lds16(WT + (size_t)(n0 + (ca0 >> 2)) * K + k0 + (ca0 & 3) * 8, Bs + w * 512);
        gl_lds16(WT + (size_t)(n0 + (ca1 >> 2)) * K + k0 + (ca1 & 3) * 8, Bs + 2048 + w * 512);
        __syncthreads();

        bf16x8 af[4], bf[4];
#pragma unroll
        for (int mt = 0; mt < 4; ++mt)
            af[mt] = *(const bf16x8*)&As[(wr * 64 + mt * 16 + n15) * 32 + quad * 8];
#pragma unroll
        for (int nt = 0; nt < 4; ++nt)
            bf[nt] = *(const bf16x8*)&Bs[(wc * 64 + nt * 16 + n15) * 32 + quad * 8];
#pragma unroll
        for (int mt = 0; mt < 4; ++mt)
#pragma unroll
            for (int nt = 0; nt < 4; ++nt)
                acc[mt][nt] = __builtin_amdgcn_mfma_f32_16x16x32_bf16(af[mt], bf[nt], acc[mt][nt], 0, 0, 0);
    }

    // epilogue: element (row, col) for acc[mt][nt][rr]:
    //   row = m0 + wr*64 + mt*16 + quad*4 + rr, col = n0 + wc*64 + nt*16 + n15
#pragma unroll
    for (int nt = 0; nt < 4; ++nt) {
        const int col = n0 + wc * 64 + nt * 16 + n15;
        const float bv = bias[col];
        if constexpr (MODE == 2) {
            const int part = col / CDIM;
            const int rem  = col - part * CDIM;
            const int h    = rem >> 6;
            const int d    = rem & 63;
#pragma unroll
            for (int mt = 0; mt < 4; ++mt)
#pragma unroll
                for (int rr = 0; rr < 4; ++rr) {
                    const int r  = m0 + wr * 64 + mt * 16 + quad * 4 + rr;
                    const int bi = r >> 11;
                    const int n  = r & 2047;
                    const short v = f2bf(acc[mt][nt][rr] + bv);
                    if (part == 0)
                        qb[((size_t)(bi * HEADS + h) * SEQ + n) * DH + d] = v;
                    else if (part == 1)
                        kb[((size_t)(bi * HEADS + h) * SEQ + n) * DH + d] = v;
                    else
                        vtb[((size_t)(bi * HEADS + h) * DH + d) * SEQ + n] = v;
                }
        } else {
#pragma unroll
            for (int mt = 0; mt < 4; ++mt)
#pragma unroll
                for (int rr = 0; rr < 4; ++rr) {
                    const int r = m0 + wr * 64 + mt * 16 + quad * 4 + rr;
                    float o = acc[mt][nt][rr] + bv;
                    if constexpr (MODE == 1) {
                        outB[(size_t)r * N + col] = f2bf(gelu_exact(o));
                    } else {
                        if (resid) o += resid[(size_t)r * N + col];
                        outF[(size_t)r * N + col] = o;
                    }
                }
        }
    }
}

// -------------------- bf16 MFMA flash attention --------------------
// grid (SEQ/64, HEADS, B), block 256 (4 waves). Wave w owns q-rows w*16..w*16+15.
// Q,K: bf16 [B,H,N,DH] row-major; Vt: bf16 [B,H,DH,N]. Output bf16 [tok][384].
__global__ __launch_bounds__(256) void attn_mfma(const short* __restrict__ qb,
                                                 const short* __restrict__ kb,
                                                 const short* __restrict__ vtb,
                                                 short* __restrict__ outp) {
    __shared__ __align__(16) short Ql[64 * 64];       // [q][d]
    __shared__ __align__(16) short Kl[64 * 64];       // [kcol][d]
    __shared__ __align__(16) short Vtl[64 * 64];      // [d][kcol]
    __shared__ __align__(16) short Pl[4 * 16 * 72];   // per-wave [q16][k64+pad8]

    const int qt = blockIdx.x;
    const int h  = blockIdx.y;
    const int b  = blockIdx.z;
    const int bh = b * HEADS + h;

    const int tid  = threadIdx.x;
    const int w    = tid >> 6;
    const int lane = tid & 63;
    const int quad = lane >> 4;
    const int n15  = lane & 15;

    const size_t headoff = (size_t)bh * SEQ * DH;   // shorts

    {
        const short* qg = qb + headoff + (size_t)qt * 64 * DH;
#pragma unroll
        for (int i = 0; i < 2; ++i) {
            const int c = (w * 2 + i) * 512;
            gl_lds16(qg + c + lane * 8, Ql + c);
        }
    }

    f32x4 O[4];
    float m[4], l[4];
#pragma unroll
    for (int nt = 0; nt < 4; ++nt) { O[nt][0] = 0; O[nt][1] = 0; O[nt][2] = 0; O[nt][3] = 0; }
#pragma unroll
    for (int r = 0; r < 4; ++r) { m[r] = -1e30f; l[r] = 0.0f; }

    bf16x8 qf[2];
    short* myPl = Pl + w * (16 * 72);

    for (int kt = 0; kt < SEQ / 64; ++kt) {
        __syncthreads();
        {
            const short* kg = kb + headoff + (size_t)kt * 64 * DH;
#pragma unroll
            for (int i = 0; i < 2; ++i) {
                const int c = (w * 2 + i) * 512;
                gl_lds16(kg + c + lane * 8, Kl + c);
            }
#pragma unroll
            for (int i = 0; i < 2; ++i) {
                const int c = (w * 2 + i) * 512;
                const int o16 = (w * 2 + i) * 64 + lane;
                const int d = o16 >> 3;
                const int inr = (o16 & 7) * 8;
                const short* vg = vtb + (size_t)bh * DH * SEQ + (size_t)d * SEQ + kt * 64 + inr;
                gl_lds16(vg, Vtl + c);
            }
        }
        __syncthreads();

        if (kt == 0) {
            qf[0] = *(const bf16x8*)&Ql[(w * 16 + n15) * 64 + quad * 8];
            qf[1] = *(const bf16x8*)&Ql[(w * 16 + n15) * 64 + 32 + quad * 8];
        }

        f32x4 S[4];
#pragma unroll
        for (int nt = 0; nt < 4; ++nt) {
            S[nt][0] = 0; S[nt][1] = 0; S[nt][2] = 0; S[nt][3] = 0;
#pragma unroll
            for (int kc = 0; kc < 2; ++kc) {
                const bf16x8 kf = *(const bf16x8*)&Kl[(nt * 16 + n15) * 64 + kc * 32 + quad * 8];
                S[nt] = __builtin_amdgcn_mfma_f32_16x16x32_bf16(qf[kc], kf, S[nt], 0, 0, 0);
            }
        }

        float sc[4][4];
#pragma unroll
        for (int nt = 0; nt < 4; ++nt)
#pragma unroll
            for (int r = 0; r < 4; ++r)
                sc[nt][r] = S[nt][r] * 0.125f;

        float rm[4];
#pragma unroll
        for (int r = 0; r < 4; ++r)
            rm[r] = fmaxf(fmaxf(sc[0][r], sc[1][r]), fmaxf(sc[2][r], sc[3][r]));
#pragma unroll
        for (int off = 1; off < 16; off <<= 1)
#pragma unroll
            for (int r = 0; r < 4; ++r)
                rm[r] = fmaxf(rm[r], __shfl_xor(rm[r], off));

        float alpha[4], rs[4];
#pragma unroll
        for (int r = 0; r < 4; ++r) {
            const float mn = fmaxf(m[r], rm[r]);
            alpha[r] = __expf(m[r] - mn);
            m[r] = mn;
            float a = 0.0f;
#pragma unroll
            for (int nt = 0; nt < 4; ++nt) {
                const float p = __expf(sc[nt][r] - mn);
                sc[nt][r] = p;
                a += p;
            }
            rs[r] = a;
        }
#pragma unroll
        for (int off = 1; off < 16; off <<= 1)
#pragma unroll
            for (int r = 0; r < 4; ++r)
                rs[r] += __shfl_xor(rs[r], off);
#pragma unroll
        for (int r = 0; r < 4; ++r)
            l[r] = l[r] * alpha[r] + rs[r];

#pragma unroll
        for (int nt = 0; nt < 4; ++nt)
#pragma unroll
            for (int r = 0; r < 4; ++r) {
                O[nt][r] *= alpha[r];
                myPl[(quad * 4 + r) * 72 + nt * 16 + n15] = f2bf(sc[nt][r]);
            }

        bf16x8 pf[2];
        pf[0] = *(const bf16x8*)&myPl[n15 * 72 + quad * 8];
        pf[1] = *(const bf16x8*)&myPl[n15 * 72 + 32 + quad * 8];
#pragma unroll
        for (int nt = 0; nt < 4; ++nt) {
#pragma unroll
            for (int kc = 0; kc < 2; ++kc) {
                const bf16x8 vf = *(const bf16x8*)&Vtl[(nt * 16 + n15) * 64 + kc * 32 + quad * 8];
                O[nt] = __builtin_amdgcn_mfma_f32_16x16x32_bf16(pf[kc], vf, O[nt], 0, 0, 0);
            }
        }
    }

    float inv[4];
#pragma unroll
    for (int r = 0; r < 4; ++r) inv[r] = 1.0f / l[r];
#pragma unroll
    for (int nt = 0; nt < 4; ++nt)
#pragma unroll
        for (int r = 0; r < 4; ++r) {
            const int row = qt * 64 + w * 16 + quad * 4 + r;
            outp[(size_t)(b * SEQ + row) * CDIM + h * DH + nt * 16 + n15] = f2bf(O[nt][r] * inv[r]);
        }
}

extern "C" void kernel_launch(void* const* d_in, const int* in_sizes, int n_in,
                              void* d_out, int out_size, void* d_ws, size_t ws_size,
                              hipStream_t stream) {
    const float* x      = (const float*)d_in[0];
    const float* w_qkv  = (const float*)d_in[1];
    const float* b_qkv  = (const float*)d_in[2];
    const float* w_proj = (const float*)d_in[3];
    const float* b_proj = (const float*)d_in[4];
    const float* w_fc1  = (const float*)d_in[5];
    const float* b_fc1  = (const float*)d_in[6];
    const float* w_fc2  = (const float*)d_in[7];
    const float* b_fc2  = (const float*)d_in[8];
    const float* g1     = (const float*)d_in[9];
    const float* beta1  = (const float*)d_in[10];
    const float* g2     = (const float*)d_in[11];
    const float* beta2  = (const float*)d_in[12];
    float* out = (float*)d_out;

    // ws layout (all bf16/shorts, disjoint, 60.2 MB total):
    short* qkvT = (short*)d_ws;                         // [1152][384]
    short* projT = qkvT + 1152 * 384;                   // [384][384]
    short* fc1T  = projT + 384 * 384;                   // [1536][384]
    short* fc2T  = fc1T + 1536 * 384;                   // [384][1536]
    short* y     = fc2T + 384 * 1536;                   // [TOK][384]
    short* qb    = y + (size_t)TOK * 384;
    short* kb    = qb + (size_t)TOK * 384;
    short* vtb   = kb + (size_t)TOK * 384;
    short* attn  = vtb + (size_t)TOK * 384;             // [TOK][384]
    short* hbuf  = attn + (size_t)TOK * 384;            // [TOK][1536]

    // 0) weights -> bf16 transposed
    transpose_bf16<<<dim3(1152 / 32, 384 / 32), 256, 0, stream>>>(w_qkv, qkvT, CDIM, 3 * CDIM);
    transpose_bf16<<<dim3(384 / 32, 384 / 32), 256, 0, stream>>>(w_proj, projT, CDIM, CDIM);
    transpose_bf16<<<dim3(1536 / 32, 384 / 32), 256, 0, stream>>>(w_fc1, fc1T, CDIM, HID);
    transpose_bf16<<<dim3(384 / 32, 1536 / 32), 256, 0, stream>>>(w_fc2, fc2T, HID, CDIM);

    // 1) y = bf16(LN(x, g1, beta1))
    ln_kernel<<<TOK, 128, 0, stream>>>(x, g1, beta1, y);
    // 2) q/k/vt = y @ w_qkv + b_qkv   (MFMA, scatter epilogue)
    mfma_gemm<2><<<dim3(1152 / 128, TOK / 128), 256, 0, stream>>>(
        y, qkvT, b_qkv, nullptr, nullptr, nullptr, qb, kb, vtb, TOK, 3 * CDIM, CDIM);
    // 3) attn = flash_attention(q, k, vt) -> bf16
    attn_mfma<<<dim3(SEQ / 64, HEADS, 4), 256, 0, stream>>>(qb, kb, vtb, attn);
    // 4) out(x1) = x + attn @ w_proj + b_proj
    mfma_gemm<0><<<dim3(CDIM / 128, TOK / 128), 256, 0, stream>>>(
        attn, projT, b_proj, x, out, nullptr, nullptr, nullptr, nullptr, TOK, CDIM, CDIM);
    // 5) y = bf16(LN(out, g2, beta2))
    ln_kernel<<<TOK, 128, 0, stream>>>(out, g2, beta2, y);
    // 6) h = bf16(gelu(y @ w_fc1 + b_fc1))
    mfma_gemm<1><<<dim3(HID / 128, TOK / 128), 256, 0, stream>>>(
        y, fc1T, b_fc1, nullptr, nullptr, hbuf, nullptr, nullptr, nullptr, TOK, HID, CDIM);
    // 7) out = x1 + h @ w_fc2 + b_fc2  (in-place residual)
    mfma_gemm<0><<<dim3(CDIM / 128, TOK / 128), 256, 0, stream>>>(
        hbuf, fc2T, b_fc2, out, out, nullptr, nullptr, nullptr, nullptr, TOK, CDIM, HID);
}

// Round 4
// 278.638 us; speedup vs baseline: 4.0208x; 1.2364x over previous
//
#include <hip/hip_runtime.h>
#include <hip/hip_bf16.h>

#define TOK 8192      // B*N
#define CDIM 384
#define HEADS 6
#define DH 64
#define HID 1536
#define SEQ 2048

typedef short bf16x8 __attribute__((ext_vector_type(8)));
typedef float f32x4 __attribute__((ext_vector_type(4)));
typedef void __attribute__((address_space(1))) GV;
typedef void __attribute__((address_space(3))) SV;

__device__ __forceinline__ short f2bf(float f) {
    __hip_bfloat16 h = __float2bfloat16(f);
    return *reinterpret_cast<short*>(&h);
}

__device__ __forceinline__ int pack_bf2(float a, float b) {
    __hip_bfloat162 h2 = __float22bfloat162_rn(make_float2(a, b));
    int r;
    __builtin_memcpy(&r, &h2, 4);
    return r;
}

__device__ __forceinline__ void gl_lds16(const short* g, short* lds) {
    // wave-collective: lane i's 16B -> lds_base + i*16 (lds must be wave-uniform)
    __builtin_amdgcn_global_load_lds((GV*)g, (SV*)lds, 16, 0, 0);
}

__device__ __forceinline__ float gelu_exact(float v) {
    return 0.5f * v * (1.0f + erff(v * 0.70710678118654752f));
}

// GEMM LDS swizzle: rows are 64B (4 chunks); spread across banks + row-parity
#define SWZ4(r) ((((r) & 3) ^ (((r) >> 2) & 3)))

// -------------------- LayerNorm: fp32 in, bf16 out --------------------
__global__ __launch_bounds__(128) void ln_kernel(const float* __restrict__ x,
                                                 const float* __restrict__ g,
                                                 const float* __restrict__ bta,
                                                 short* __restrict__ y) {
    const int row = blockIdx.x;
    const float* xr = x + (size_t)row * CDIM;
    const int t = threadIdx.x;
    float v0 = xr[t], v1 = xr[t + 128], v2 = xr[t + 256];
    float s = v0 + v1 + v2;
    float ss = v0 * v0 + v1 * v1 + v2 * v2;
#pragma unroll
    for (int off = 1; off < 64; off <<= 1) {
        s += __shfl_xor(s, off);
        ss += __shfl_xor(ss, off);
    }
    __shared__ float sh[4];
    const int wv = t >> 6;
    if ((t & 63) == 0) { sh[wv] = s; sh[2 + wv] = ss; }
    __syncthreads();
    s = sh[0] + sh[1];
    ss = sh[2] + sh[3];
    const float mu = s * (1.0f / CDIM);
    const float var = ss * (1.0f / CDIM) - mu * mu;
    const float rs = rsqrtf(var + 1e-6f);
    short* yr = y + (size_t)row * CDIM;
    yr[t]       = f2bf((v0 - mu) * rs * g[t]       + bta[t]);
    yr[t + 128] = f2bf((v1 - mu) * rs * g[t + 128] + bta[t + 128]);
    yr[t + 256] = f2bf((v2 - mu) * rs * g[t + 256] + bta[t + 256]);
}

// -------------------- weight transpose+convert: wT[n][k] = bf16(w[k][n]) ----------
__global__ __launch_bounds__(256) void transpose_bf16(const float* __restrict__ w,
                                                      short* __restrict__ wT,
                                                      int K, int N) {
    __shared__ float t[32][33];
    const int bx = blockIdx.x * 32, by = blockIdx.y * 32;
    const int tx = threadIdx.x & 31, ty = threadIdx.x >> 5;
#pragma unroll
    for (int i = 0; i < 4; ++i)
        t[ty + i * 8][tx] = w[(size_t)(by + ty + i * 8) * N + bx + tx];
    __syncthreads();
#pragma unroll
    for (int i = 0; i < 4; ++i)
        wT[(size_t)(bx + ty + i * 8) * K + by + tx] = f2bf(t[tx][ty + i * 8]);
}

// -------------------- bf16 MFMA GEMM: C = A[M,K] @ WT[N,K]^T + bias ----------------
// MT=4: 128x128 tile, waves 2x2 (64x64 each). MT=2: 128x64 tile, waves 4x1 (32x64 each).
// MODE 0: fp32 out (+optional resid).  MODE 1: gelu -> bf16 out.  MODE 2: qkv scatter.
template <int MODE, int MT>
__global__ __launch_bounds__(256) void mfma_gemm(const short* __restrict__ A,
                                                 const short* __restrict__ WT,
                                                 const float* __restrict__ bias,
                                                 const float* __restrict__ resid,
                                                 float* __restrict__ outF,
                                                 short* __restrict__ outB,
                                                 short* __restrict__ qb,
                                                 short* __restrict__ kb,
                                                 short* __restrict__ vtb,
                                                 int M, int N, int K) {
    constexpr int BN = (MT == 4) ? 128 : 64;
    __shared__ __align__(16) short As[128 * 32];
    __shared__ __align__(16) short Bs[BN * 32];

    const int tid  = threadIdx.x;
    const int w    = tid >> 6;
    const int lane = tid & 63;
    const int quad = lane >> 4;
    const int n15  = lane & 15;
    const int wr   = (MT == 4) ? (w >> 1) : w;
    const int wc   = (MT == 4) ? (w & 1) : 0;
    const int m0   = blockIdx.y * 128;
    const int n0   = blockIdx.x * BN;

    f32x4 acc[MT][4];
#pragma unroll
    for (int i = 0; i < MT; ++i)
#pragma unroll
        for (int j = 0; j < 4; ++j) {
            acc[i][j][0] = 0; acc[i][j][1] = 0; acc[i][j][2] = 0; acc[i][j][3] = 0;
        }

    const int ca0 = tid, ca1 = tid + 256;
    const int swz = SWZ4(n15);   // fragment-read swizzle (row bits from n15 only)

    for (int k0 = 0; k0 < K; k0 += 32) {
        __syncthreads();
        gl_lds16(A  + (size_t)(m0 + (ca0 >> 2)) * K + k0 + (((ca0 & 3) ^ SWZ4(ca0 >> 2)) * 8), As + w * 512);
        gl_lds16(A  + (size_t)(m0 + (ca1 >> 2)) * K + k0 + (((ca1 & 3) ^ SWZ4(ca1 >> 2)) * 8), As + 2048 + w * 512);
        gl_lds16(WT + (size_t)(n0 + (ca0 >> 2)) * K + k0 + (((ca0 & 3) ^ SWZ4(ca0 >> 2)) * 8), Bs + w * 512);
        if (MT == 4)
            gl_lds16(WT + (size_t)(n0 + (ca1 >> 2)) * K + k0 + (((ca1 & 3) ^ SWZ4(ca1 >> 2)) * 8), Bs + 2048 + w * 512);
        __syncthreads();

        bf16x8 af[MT], bfr[4];
#pragma unroll
        for (int mt = 0; mt < MT; ++mt)
            af[mt] = *(const bf16x8*)&As[(wr * (MT * 16) + mt * 16 + n15) * 32 + ((quad ^ swz) * 8)];
#pragma unroll
        for (int nt = 0; nt < 4; ++nt)
            bfr[nt] = *(const bf16x8*)&Bs[(wc * 64 + nt * 16 + n15) * 32 + ((quad ^ swz) * 8)];
#pragma unroll
        for (int mt = 0; mt < MT; ++mt)
#pragma unroll
            for (int nt = 0; nt < 4; ++nt)
                acc[mt][nt] = __builtin_amdgcn_mfma_f32_16x16x32_bf16(af[mt], bfr[nt], acc[mt][nt], 0, 0, 0);
    }

    // epilogue: row = m0 + wr*(MT*16) + mt*16 + quad*4 + rr, col = n0 + wc*64 + nt*16 + n15
#pragma unroll
    for (int nt = 0; nt < 4; ++nt) {
        const int col = n0 + wc * 64 + nt * 16 + n15;
        const float bv = bias[col];
        if constexpr (MODE == 2) {
            const int part = col / CDIM;
            const int rem  = col - part * CDIM;
            const int h    = rem >> 6;
            const int d    = rem & 63;
#pragma unroll
            for (int mt = 0; mt < MT; ++mt)
#pragma unroll
                for (int rr = 0; rr < 4; ++rr) {
                    const int r  = m0 + wr * (MT * 16) + mt * 16 + quad * 4 + rr;
                    const int bi = r >> 11;
                    const int n  = r & 2047;
                    float o = acc[mt][nt][rr] + bv;
                    if (part == 0) o *= 0.125f;   // fold attention scale into Q
                    const short v = f2bf(o);
                    if (part == 0)
                        qb[((size_t)(bi * HEADS + h) * SEQ + n) * DH + d] = v;
                    else if (part == 1)
                        kb[((size_t)(bi * HEADS + h) * SEQ + n) * DH + d] = v;
                    else
                        vtb[((size_t)(bi * HEADS + h) * DH + d) * SEQ + n] = v;
                }
        } else {
#pragma unroll
            for (int mt = 0; mt < MT; ++mt)
#pragma unroll
                for (int rr = 0; rr < 4; ++rr) {
                    const int r = m0 + wr * (MT * 16) + mt * 16 + quad * 4 + rr;
                    float o = acc[mt][nt][rr] + bv;
                    if constexpr (MODE == 1) {
                        outB[(size_t)r * N + col] = f2bf(gelu_exact(o));
                    } else {
                        if (resid) o += resid[(size_t)r * N + col];
                        outF[(size_t)r * N + col] = o;
                    }
                }
        }
    }
}

// -------------------- bf16 MFMA flash attention (S^T formulation) --------------------
// grid (SEQ/64, HEADS, B), block 256 (4 waves). Wave w owns q-rows w*16..w*16+15.
// Q,K: bf16 [B,H,N,DH] (Q pre-scaled by 1/8); Vt: bf16 [B,H,DH,N]. Out bf16 [tok][384].
// S^T = mfma(K_frag, Q_frag): lane (quad,n15) holds S[q=n15][k=nt*16+quad*4+r]
// -> per-lane softmax state (q=n15); P->A-frag via register bpermute (no LDS).
__global__ __launch_bounds__(256) void attn_mfma(const short* __restrict__ qb,
                                                 const short* __restrict__ kb,
                                                 const short* __restrict__ vtb,
                                                 short* __restrict__ outp) {
    __shared__ __align__(16) short Ql[64 * 64];       // [q][d], chunk-swizzled
    __shared__ __align__(16) short Kl[64 * 64];       // [kcol][d], chunk-swizzled
    __shared__ __align__(16) short Vtl[64 * 64];      // [d][kcol], chunk-swizzled

    const int qt = blockIdx.x;
    const int h  = blockIdx.y;
    const int b  = blockIdx.z;
    const int bh = b * HEADS + h;

    const int tid  = threadIdx.x;
    const int w    = tid >> 6;
    const int lane = tid & 63;
    const int quad = lane >> 4;
    const int n15  = lane & 15;
    const int swz  = n15 & 7;    // row-chunk swizzle for fragment reads

    const size_t headoff = (size_t)bh * SEQ * DH;   // shorts

    // stage Q tile (swizzled: phys chunk p of row r holds logical chunk p^(r&7))
    {
        const short* qg = qb + headoff + (size_t)qt * 64 * DH;
#pragma unroll
        for (int i = 0; i < 2; ++i) {
            const int c = (w * 2 + i) * 64 + lane;           // chunk id 0..511
            const int r = c >> 3, p = c & 7;
            gl_lds16(qg + r * 64 + ((p ^ (r & 7)) * 8), Ql + c * 8 - lane * 8 + lane * 8);
        }
    }
    // NOTE: LDS dst must be wave-uniform base + lane*16; chunk id = base + lane.

    f32x4 O[4];
    float m = -1e30f, l = 0.0f;
#pragma unroll
    for (int nt = 0; nt < 4; ++nt) { O[nt][0] = 0; O[nt][1] = 0; O[nt][2] = 0; O[nt][3] = 0; }

    bf16x8 qf[2];

    for (int kt = 0; kt < SEQ / 64; ++kt) {
        __syncthreads();
        {
            const short* kg = kb + headoff + (size_t)kt * 64 * DH;
#pragma unroll
            for (int i = 0; i < 2; ++i) {
                const int c = (w * 2 + i) * 64 + lane;
                const int r = c >> 3, p = c & 7;
                gl_lds16(kg + r * 64 + ((p ^ (r & 7)) * 8), Kl + (c - lane) * 8);
            }
            const short* vg0 = vtb + (size_t)bh * DH * SEQ + kt * 64;
#pragma unroll
            for (int i = 0; i < 2; ++i) {
                const int c = (w * 2 + i) * 64 + lane;
                const int r = c >> 3, p = c & 7;       // r = d row
                gl_lds16(vg0 + (size_t)r * SEQ + ((p ^ (r & 7)) * 8), Vtl + (c - lane) * 8);
            }
        }
        __syncthreads();

        if (kt == 0) {
            qf[0] = *(const bf16x8*)&Ql[(w * 16 + n15) * 64 + ((quad ^ swz) * 8)];
            qf[1] = *(const bf16x8*)&Ql[(w * 16 + n15) * 64 + (((4 + quad) ^ swz) * 8)];
        }

        // S^T tiles: mfma(A=K_frag, B=Q_frag) -> C[k=quad*4+r (in nt tile)][q=n15]
        f32x4 S[4];
#pragma unroll
        for (int nt = 0; nt < 4; ++nt) {
            S[nt][0] = 0; S[nt][1] = 0; S[nt][2] = 0; S[nt][3] = 0;
#pragma unroll
            for (int kc = 0; kc < 2; ++kc) {
                const bf16x8 kf = *(const bf16x8*)&Kl[(nt * 16 + n15) * 64 + (((kc * 4 + quad) ^ swz) * 8)];
                S[nt] = __builtin_amdgcn_mfma_f32_16x16x32_bf16(kf, qf[kc], S[nt], 0, 0, 0);
            }
        }

        // per-lane online softmax for q = n15 (16 k-values per lane, cross-quad reduce)
        float rm = S[0][0];
#pragma unroll
        for (int nt = 0; nt < 4; ++nt)
#pragma unroll
            for (int r = 0; r < 4; ++r)
                rm = fmaxf(rm, S[nt][r]);
        rm = fmaxf(rm, __shfl_xor(rm, 16));
        rm = fmaxf(rm, __shfl_xor(rm, 32));

        const float mn = fmaxf(m, rm);
        const float alpha = __expf(m - mn);
        m = mn;

        float rs = 0.0f;
        float sc[4][4];
#pragma unroll
        for (int nt = 0; nt < 4; ++nt)
#pragma unroll
            for (int r = 0; r < 4; ++r) {
                const float p = __expf(S[nt][r] - mn);
                sc[nt][r] = p;
                rs += p;
            }
        rs += __shfl_xor(rs, 16);
        rs += __shfl_xor(rs, 32);
        l = l * alpha + rs;

        // rescale O: O rows are q=quad*4+rr -> fetch alpha from lane (quad*4+rr)
#pragma unroll
        for (int rr = 0; rr < 4; ++rr) {
            const float aO = __shfl(alpha, quad * 4 + rr);
#pragma unroll
            for (int nt = 0; nt < 4; ++nt)
                O[nt][rr] *= aO;
        }

        // pack P (bf16 pairs) and exchange into A-fragment layout via bpermute
        int pk01[4], pk23[4];
#pragma unroll
        for (int nt = 0; nt < 4; ++nt) {
            pk01[nt] = pack_bf2(sc[nt][0], sc[nt][1]);
            pk23[nt] = pack_bf2(sc[nt][2], sc[nt][3]);
        }

#pragma unroll
        for (int kc = 0; kc < 2; ++kc) {
            const int sel01 = (quad < 2) ? pk01[2 * kc] : pk01[2 * kc + 1];
            const int sel23 = (quad < 2) ? pk23[2 * kc] : pk23[2 * kc + 1];
            const int src0 = (((2 * quad) & 3) << 4) + n15;
            const int src1 = (((2 * quad + 1) & 3) << 4) + n15;
            int aw[4];
            aw[0] = __shfl(sel01, src0);
            aw[1] = __shfl(sel23, src0);
            aw[2] = __shfl(sel01, src1);
            aw[3] = __shfl(sel23, src1);
            bf16x8 af;
            __builtin_memcpy(&af, aw, 16);
#pragma unroll
            for (int nt = 0; nt < 4; ++nt) {
                const bf16x8 vf = *(const bf16x8*)&Vtl[(nt * 16 + n15) * 64 + (((kc * 4 + quad) ^ swz) * 8)];
                O[nt] = __builtin_amdgcn_mfma_f32_16x16x32_bf16(af, vf, O[nt], 0, 0, 0);
            }
        }
    }

    const float invq = 1.0f / l;
#pragma unroll
    for (int rr = 0; rr < 4; ++rr) {
        const float inv = __shfl(invq, quad * 4 + rr);
        const int row = qt * 64 + w * 16 + quad * 4 + rr;
#pragma unroll
        for (int nt = 0; nt < 4; ++nt)
            outp[(size_t)(b * SEQ + row) * CDIM + h * DH + nt * 16 + n15] = f2bf(O[nt][rr] * inv);
    }
}

extern "C" void kernel_launch(void* const* d_in, const int* in_sizes, int n_in,
                              void* d_out, int out_size, void* d_ws, size_t ws_size,
                              hipStream_t stream) {
    const float* x      = (const float*)d_in[0];
    const float* w_qkv  = (const float*)d_in[1];
    const float* b_qkv  = (const float*)d_in[2];
    const float* w_proj = (const float*)d_in[3];
    const float* b_proj = (const float*)d_in[4];
    const float* w_fc1  = (const float*)d_in[5];
    const float* b_fc1  = (const float*)d_in[6];
    const float* w_fc2  = (const float*)d_in[7];
    const float* b_fc2  = (const float*)d_in[8];
    const float* g1     = (const float*)d_in[9];
    const float* beta1  = (const float*)d_in[10];
    const float* g2     = (const float*)d_in[11];
    const float* beta2  = (const float*)d_in[12];
    float* out = (float*)d_out;

    short* qkvT = (short*)d_ws;                         // [1152][384]
    short* projT = qkvT + 1152 * 384;                   // [384][384]
    short* fc1T  = projT + 384 * 384;                   // [1536][384]
    short* fc2T  = fc1T + 1536 * 384;                   // [384][1536]
    short* y     = fc2T + 384 * 1536;                   // [TOK][384]
    short* qb    = y + (size_t)TOK * 384;
    short* kb    = qb + (size_t)TOK * 384;
    short* vtb   = kb + (size_t)TOK * 384;
    short* attn  = vtb + (size_t)TOK * 384;             // [TOK][384]
    short* hbuf  = attn + (size_t)TOK * 384;            // [TOK][1536]

    transpose_bf16<<<dim3(1152 / 32, 384 / 32), 256, 0, stream>>>(w_qkv, qkvT, CDIM, 3 * CDIM);
    transpose_bf16<<<dim3(384 / 32, 384 / 32), 256, 0, stream>>>(w_proj, projT, CDIM, CDIM);
    transpose_bf16<<<dim3(1536 / 32, 384 / 32), 256, 0, stream>>>(w_fc1, fc1T, CDIM, HID);
    transpose_bf16<<<dim3(384 / 32, 1536 / 32), 256, 0, stream>>>(w_fc2, fc2T, HID, CDIM);

    ln_kernel<<<TOK, 128, 0, stream>>>(x, g1, beta1, y);
    mfma_gemm<2, 4><<<dim3(1152 / 128, TOK / 128), 256, 0, stream>>>(
        y, qkvT, b_qkv, nullptr, nullptr, nullptr, qb, kb, vtb, TOK, 3 * CDIM, CDIM);
    attn_mfma<<<dim3(SEQ / 64, HEADS, 4), 256, 0, stream>>>(qb, kb, vtb, attn);
    mfma_gemm<0, 2><<<dim3(CDIM / 64, TOK / 128), 256, 0, stream>>>(
        attn, projT, b_proj, x, out, nullptr, nullptr, nullptr, nullptr, TOK, CDIM, CDIM);
    ln_kernel<<<TOK, 128, 0, stream>>>(out, g2, beta2, y);
    mfma_gemm<1, 4><<<dim3(HID / 128, TOK / 128), 256, 0, stream>>>(
        y, fc1T, b_fc1, nullptr, nullptr, hbuf, nullptr, nullptr, nullptr, TOK, HID, CDIM);
    mfma_gemm<0, 2><<<dim3(CDIM / 64, TOK / 128), 256, 0, stream>>>(
        hbuf, fc2T, b_fc2, out, out, nullptr, nullptr, nullptr, nullptr, TOK, CDIM, HID);
}